// Round 1
// baseline (909.889 us; speedup 1.0000x reference)
//
#include <hip/hip_runtime.h>
#include <hip/hip_bf16.h>
#include <cstddef>
#include <cstdint>

// LinearQuantized: out = fake_quant_i8(x) @ fake_quant_i8(W)^T + bias
// x: [M=16384, K=4096] f32, W: [N=4096, K=4096] f32, bias: [N] f32, out: [M,N] f32
//
// Strategy: absmax-reduce -> int8 quantize to scratch -> int8 MFMA GEMM
// (m97-style 128x128 tile, BK=64, global_load_lds width-16 staging),
// epilogue: acc_i32 * (sx*sw) + bias.

typedef int i32x4 __attribute__((ext_vector_type(4)));

__device__ __forceinline__ void async16(const void* g, void* l) {
    __builtin_amdgcn_global_load_lds(
        (const __attribute__((address_space(1))) void*)g,
        (__attribute__((address_space(3))) void*)l,
        16, 0, 0);
}

// ---------------- absmax reduction ----------------
__global__ void absmax_kernel(const float* __restrict__ in, unsigned int n4,
                              unsigned int* __restrict__ out_bits) {
    const float4* in4 = (const float4*)in;
    float m = 0.0f;
    for (unsigned int i = blockIdx.x * blockDim.x + threadIdx.x; i < n4;
         i += gridDim.x * blockDim.x) {
        float4 v = in4[i];
        m = fmaxf(m, fmaxf(fmaxf(fabsf(v.x), fabsf(v.y)),
                           fmaxf(fabsf(v.z), fabsf(v.w))));
    }
    // wave-64 butterfly reduce
    #pragma unroll
    for (int o = 32; o > 0; o >>= 1)
        m = fmaxf(m, __shfl_xor(m, o));
    __shared__ float wmax[8];
    int lane = threadIdx.x & 63;
    int wv = threadIdx.x >> 6;
    if (lane == 0) wmax[wv] = m;
    __syncthreads();
    if (threadIdx.x == 0) {
        int nw = blockDim.x >> 6;
        float b = wmax[0];
        for (int i = 1; i < nw; ++i) b = fmaxf(b, wmax[i]);
        // abs values are >= 0, so IEEE float order == uint order
        atomicMax(out_bits, __float_as_uint(b));
    }
}

// ---------------- quantize f32 -> i8 ----------------
__global__ void quant_kernel(const float* __restrict__ in, char* __restrict__ out,
                             unsigned int n4,
                             const unsigned int* __restrict__ absmax_bits) {
    float s = fmaxf(__uint_as_float(*absmax_bits) / 127.0f, 1e-8f);
    const float4* in4 = (const float4*)in;
    char4* out4 = (char4*)out;
    for (unsigned int i = blockIdx.x * blockDim.x + threadIdx.x; i < n4;
         i += gridDim.x * blockDim.x) {
        float4 v = in4[i];
        char4 q;
        q.x = (char)(int)fminf(fmaxf(rintf(v.x / s), -127.0f), 127.0f);
        q.y = (char)(int)fminf(fmaxf(rintf(v.y / s), -127.0f), 127.0f);
        q.z = (char)(int)fminf(fmaxf(rintf(v.z / s), -127.0f), 127.0f);
        q.w = (char)(int)fminf(fmaxf(rintf(v.w / s), -127.0f), 127.0f);
        out4[i] = q;
    }
}

// ---------------- int8 GEMM: C[m][n] = s * sum_k Aq[m][k]*Bq[n][k] + bias[n] ----------------
// 128x128 block tile, BK=64, 256 threads = 4 waves in 2x2 grid,
// each wave: 4x4 tiles of 16x16 (v_mfma_i32_16x16x64_i8).
#define BM 128
#define BN 128
#define BK 64

__global__ __launch_bounds__(256) void gemm_i8_kernel(
    const char* __restrict__ Aq, const char* __restrict__ Bq,
    const float* __restrict__ bias, float* __restrict__ C,
    const unsigned int* __restrict__ scale_bits, int M, int N, int K) {
    __shared__ char sA[BM * BK];  // 8 KiB, row-major [128][64]
    __shared__ char sB[BN * BK];  // 8 KiB

    const int t = threadIdx.x;
    const int lane = t & 63;
    const int wave = t >> 6;
    const int wm = wave >> 1;  // 0..1
    const int wn = wave & 1;   // 0..1

    const int m0 = blockIdx.y * BM;
    const int n0 = blockIdx.x * BN;

    // staging: thread t loads 16B chunk c = t and c = t+256 for each matrix
    // chunk c -> row c/4 (0..127), byte col (c%4)*16; LDS offset c*16 (lane-contiguous)
    const int ar = t >> 2;         // 0..63
    const int ac = (t & 3) * 16;   // 0/16/32/48

    const char* gA0 = Aq + (size_t)(m0 + ar) * K + ac;
    const char* gA1 = Aq + (size_t)(m0 + ar + 64) * K + ac;
    const char* gB0 = Bq + (size_t)(n0 + ar) * K + ac;
    const char* gB1 = Bq + (size_t)(n0 + ar + 64) * K + ac;

    i32x4 acc[4][4] = {};

    const int lr = lane & 15;   // fragment row/col within 16
    const int kg = lane >> 4;   // k-group 0..3 (16 bytes each)

    for (int k0 = 0; k0 < K; k0 += BK) {
        async16(gA0 + k0, sA + t * 16);
        async16(gA1 + k0, sA + (t + 256) * 16);
        async16(gB0 + k0, sB + t * 16);
        async16(gB1 + k0, sB + (t + 256) * 16);
        __syncthreads();  // drains vmcnt (compiler emits full waitcnt before barrier)

        i32x4 af[4], bf[4];
        #pragma unroll
        for (int i = 0; i < 4; ++i) {
            af[i] = *(const i32x4*)(sA + (wm * 64 + i * 16 + lr) * BK + kg * 16);
            bf[i] = *(const i32x4*)(sB + (wn * 64 + i * 16 + lr) * BK + kg * 16);
        }
        #pragma unroll
        for (int i = 0; i < 4; ++i)
            #pragma unroll
            for (int j = 0; j < 4; ++j)
                acc[i][j] = __builtin_amdgcn_mfma_i32_16x16x64_i8(
                    af[i], bf[j], acc[i][j], 0, 0, 0);
        __syncthreads();
    }

    float sx = fmaxf(__uint_as_float(scale_bits[0]) / 127.0f, 1e-8f);
    float sw = fmaxf(__uint_as_float(scale_bits[1]) / 127.0f, 1e-8f);
    float s = sx * sw;

    // C/D layout (16x16, shape-determined): col = lane&15, row = (lane>>4)*4 + reg
    #pragma unroll
    for (int i = 0; i < 4; ++i) {
        int row = m0 + wm * 64 + i * 16 + kg * 4;
        #pragma unroll
        for (int j = 0; j < 4; ++j) {
            int col = n0 + wn * 64 + j * 16 + lr;
            float bv = bias[col];
            float* Cp = C + (size_t)row * N + col;
            #pragma unroll
            for (int r = 0; r < 4; ++r)
                Cp[(size_t)r * N] = (float)acc[i][j][r] * s + bv;
        }
    }
}

extern "C" void kernel_launch(void* const* d_in, const int* in_sizes, int n_in,
                              void* d_out, int out_size, void* d_ws, size_t ws_size,
                              hipStream_t stream) {
    const float* x = (const float*)d_in[0];
    const float* w = (const float*)d_in[1];
    const float* bias = (const float*)d_in[2];
    float* out = (float*)d_out;

    const int N = in_sizes[2];                 // 4096
    const int K = in_sizes[1] / N;             // 4096
    const int M = in_sizes[0] / K;             // 16384

    // workspace layout
    unsigned int* scale_bits = (unsigned int*)d_ws;          // [0]=absmax_x bits, [1]=absmax_w bits
    char* xq = (char*)d_ws + 256;                            // M*K int8
    char* wq = xq + (size_t)M * K;                           // N*K int8

    const unsigned int nx4 = (unsigned int)((size_t)M * K / 4);
    const unsigned int nw4 = (unsigned int)((size_t)N * K / 4);

    hipMemsetAsync(d_ws, 0, 16, stream);

    absmax_kernel<<<2048, 256, 0, stream>>>(x, nx4, scale_bits + 0);
    absmax_kernel<<<1024, 256, 0, stream>>>(w, nw4, scale_bits + 1);

    quant_kernel<<<2048, 256, 0, stream>>>(x, xq, nx4, scale_bits + 0);
    quant_kernel<<<1024, 256, 0, stream>>>(w, wq, nw4, scale_bits + 1);

    dim3 grid(N / BN, M / BM);
    gemm_i8_kernel<<<grid, 256, 0, stream>>>(xq, wq, bias, out, scale_bits, M, N, K);
}